// Round 1
// baseline (363.232 us; speedup 1.0000x reference)
//
#include <hip/hip_runtime.h>
#include <cstdint>

static constexpr int Nn = 8192;
static constexpr int Dd = 128;
static constexpr float MARGINf = 1.0f;
static constexpr float EPSf = 1e-6f;
static constexpr float FMAXf = 3.4028234663852886e38f;

typedef unsigned long long u64;

// Monotonic map fp32 -> u32 (total order matching float compare; +0 > -0 which
// only differs from IEEE-equal ties in measure-zero cases).
__device__ __forceinline__ unsigned fkey(float f) {
  unsigned b = __float_as_uint(f);
  return (b & 0x80000000u) ? ~b : (b | 0x80000000u);
}

// One wave per row: squared norm + init of the packed argmax/argmin cells.
__global__ __launch_bounds__(256) void k_norm(const float* __restrict__ E,
                                              float* __restrict__ norm,
                                              u64* __restrict__ posPack,
                                              u64* __restrict__ negPack) {
  int row = (blockIdx.x * 256 + threadIdx.x) >> 6;
  int l = threadIdx.x & 63;
  float2 v = *(const float2*)(E + row * Dd + l * 2);
  float s = v.x * v.x + v.y * v.y;
  #pragma unroll
  for (int off = 32; off; off >>= 1) s += __shfl_xor(s, off);
  if (l == 0) {
    norm[row] = s;
    posPack[row] = 0ull;
    negPack[row] = ~0ull;
  }
}

// 64x64 distance tile + fused masked arg-reductions.
__global__ __launch_bounds__(256) void k_tile(const float* __restrict__ E,
                                              const int* __restrict__ lab,
                                              const float* __restrict__ norm,
                                              u64* __restrict__ posPack,
                                              u64* __restrict__ negPack) {
  __shared__ float As[64 * 132];
  __shared__ float Bs[64 * 132];
  __shared__ float nI[64], nJ[64];
  __shared__ int lI[64], lJ[64];

  const int t = threadIdx.x;
  const int ibase = blockIdx.x * 64, jbase = blockIdx.y * 64;

  #pragma unroll
  for (int q = 0; q < 8; ++q) {
    int idx = q * 256 + t;
    int row = idx >> 5, c4 = (idx & 31) * 4;
    *(float4*)(As + row * 132 + c4) = *(const float4*)(E + (ibase + row) * Dd + c4);
    *(float4*)(Bs + row * 132 + c4) = *(const float4*)(E + (jbase + row) * Dd + c4);
  }
  if (t < 64) {
    nI[t] = norm[ibase + t];
    lI[t] = lab[ibase + t];
  } else if (t < 128) {
    int u = t - 64;
    nJ[u] = norm[jbase + u];
    lJ[u] = lab[jbase + u];
  }
  __syncthreads();

  const int tx = t & 15, ty = t >> 4;
  float acc[4][4];
  #pragma unroll
  for (int rr = 0; rr < 4; ++rr)
    #pragma unroll
    for (int cc = 0; cc < 4; ++cc) acc[rr][cc] = 0.f;

  #pragma unroll 8
  for (int kk = 0; kk < 32; ++kk) {
    float4 a[4], b[4];
    #pragma unroll
    for (int rr = 0; rr < 4; ++rr)
      a[rr] = *(const float4*)(As + (ty + 16 * rr) * 132 + kk * 4);
    #pragma unroll
    for (int cc = 0; cc < 4; ++cc)
      b[cc] = *(const float4*)(Bs + (tx + 16 * cc) * 132 + kk * 4);
    #pragma unroll
    for (int rr = 0; rr < 4; ++rr)
      #pragma unroll
      for (int cc = 0; cc < 4; ++cc)
        acc[rr][cc] += a[rr].x * b[cc].x + a[rr].y * b[cc].y +
                       a[rr].z * b[cc].z + a[rr].w * b[cc].w;
  }

  #pragma unroll
  for (int rr = 0; rr < 4; ++rr) {
    const int r = ty + 16 * rr;
    const int gi = ibase + r;
    const float ni = nI[r];
    const int li = lI[r];
    u64 pp = 0ull, np = ~0ull;
    #pragma unroll
    for (int cc = 0; cc < 4; ++cc) {
      const int c = tx + 16 * cc;
      const int gj = jbase + c;
      float dist = (ni - 2.0f * acc[rr][cc]) + nJ[c];
      bool sim = (li == lJ[c]);
      float pv = sim ? dist : 0.0f;
      float nv = sim ? FMAXf : (dist <= 0.0f ? dist + FMAXf : dist);
      u64 pc = ((u64)fkey(pv) << 32) | (u64)(0xFFFFFFFFu - (unsigned)gj);
      u64 nc = ((u64)fkey(nv) << 32) | (u64)(unsigned)gj;
      pp = pp > pc ? pp : pc;
      np = np < nc ? np : nc;
    }
    #pragma unroll
    for (int off = 1; off < 16; off <<= 1) {
      u64 op = __shfl_xor(pp, off);
      u64 on = __shfl_xor(np, off);
      pp = pp > op ? pp : op;
      np = np < on ? np : on;
    }
    if (tx == 0) {
      atomicMax(posPack + gi, pp);
      atomicMin(negPack + gi, np);
    }
  }
}

// One wave per row: exact triplet term from the selected indices.
__global__ __launch_bounds__(256) void k_final(const float* __restrict__ E,
                                               const u64* __restrict__ posPack,
                                               const u64* __restrict__ negPack,
                                               float* __restrict__ rowLoss) {
  int i = (blockIdx.x * 256 + threadIdx.x) >> 6;
  int l = threadIdx.x & 63;
  int jp = (int)(0xFFFFFFFFu - (unsigned)(posPack[i] & 0xFFFFFFFFull));
  int jn = (int)(unsigned)(negPack[i] & 0xFFFFFFFFull);
  float2 a = *(const float2*)(E + i * Dd + l * 2);
  float2 p = *(const float2*)(E + jp * Dd + l * 2);
  float2 n = *(const float2*)(E + jn * Dd + l * 2);
  float dx = a.x - p.x + EPSf, dy = a.y - p.y + EPSf;
  float sap = dx * dx + dy * dy;
  dx = a.x - n.x + EPSf;
  dy = a.y - n.y + EPSf;
  float san = dx * dx + dy * dy;
  #pragma unroll
  for (int off = 32; off; off >>= 1) {
    sap += __shfl_xor(sap, off);
    san += __shfl_xor(san, off);
  }
  if (l == 0) rowLoss[i] = fmaxf(sqrtf(sap) - sqrtf(san) + MARGINf, 0.0f);
}

// Deterministic tree reduction -> mean.
__global__ __launch_bounds__(256) void k_reduce(const float* __restrict__ rowLoss,
                                                float* __restrict__ out) {
  __shared__ float s[256];
  int t = threadIdx.x;
  float sum = 0.f;
  for (int q = 0; q < 32; ++q) sum += rowLoss[t + 256 * q];
  s[t] = sum;
  __syncthreads();
  for (int off = 128; off; off >>= 1) {
    if (t < off) s[t] += s[t + off];
    __syncthreads();
  }
  if (t == 0) out[0] = s[0] * (1.0f / 8192.0f);  // /8192 exact (pow2)
}

extern "C" void kernel_launch(void* const* d_in, const int* in_sizes, int n_in,
                              void* d_out, int out_size, void* d_ws, size_t ws_size,
                              hipStream_t stream) {
  const float* E = (const float*)d_in[0];
  const int* lab = (const int*)d_in[1];
  float* out = (float*)d_out;

  char* w = (char*)d_ws;
  u64* posPack = (u64*)w;                    // 64 KB
  u64* negPack = (u64*)(w + 65536);          // 64 KB
  float* norm = (float*)(w + 131072);        // 32 KB
  float* rowLoss = (float*)(w + 163840);     // 32 KB

  k_norm<<<2048, 256, 0, stream>>>(E, norm, posPack, negPack);
  k_tile<<<dim3(128, 128), 256, 0, stream>>>(E, lab, norm, posPack, negPack);
  k_final<<<2048, 256, 0, stream>>>(E, posPack, negPack, rowLoss);
  k_reduce<<<1, 256, 0, stream>>>(rowLoss, out);
}

// Round 2
// 56.406 us; speedup vs baseline: 6.4396x; 6.4396x over previous
//
#include <hip/hip_runtime.h>
#include <cstdint>

typedef unsigned long long u64;
typedef _Float16 half8 __attribute__((ext_vector_type(8)));
typedef float f32x16 __attribute__((ext_vector_type(16)));

static constexpr int Dd = 128;
static constexpr float EPSf = 1e-6f;
static constexpr float MARGINf = 1.0f;

// Monotonic map fp32 -> u32 (total order matching float compare).
__device__ __forceinline__ unsigned fkey(float f) {
  unsigned b = __float_as_uint(f);
  return (b & 0x80000000u) ? ~b : (b | 0x80000000u);
}

// One wave per row: fp32 norm (exact), fp16 convert, norm+label pack, init packs.
__global__ __launch_bounds__(256) void k_prep(const float* __restrict__ E,
                                              const int* __restrict__ lab,
                                              _Float16* __restrict__ Eh,
                                              float2* __restrict__ nl,
                                              u64* __restrict__ posPack,
                                              u64* __restrict__ negPack) {
  int row = (blockIdx.x * 256 + threadIdx.x) >> 6;
  int l = threadIdx.x & 63;
  float2 v = *(const float2*)(E + row * Dd + l * 2);
  union { _Float16 h[2]; unsigned u; } cv;
  cv.h[0] = (_Float16)v.x;
  cv.h[1] = (_Float16)v.y;
  *(unsigned*)(Eh + row * Dd + l * 2) = cv.u;
  float s = v.x * v.x + v.y * v.y;
  #pragma unroll
  for (int off = 32; off; off >>= 1) s += __shfl_xor(s, off);
  if (l == 0) {
    float2 q;
    q.x = s;
    q.y = __int_as_float(lab[row]);
    nl[row] = q;
    posPack[row] = 0ull;
    negPack[row] = ~0ull;
  }
}

// 256x256 pair tile: Gram via f16 MFMA (transposed: rows=j, cols=i) + fused
// per-lane masked arg-reductions.
__global__ __launch_bounds__(512, 2) void k_gemm(const _Float16* __restrict__ Eh,
                                                 const float2* __restrict__ nl,
                                                 const int* __restrict__ lab,
                                                 u64* __restrict__ posPack,
                                                 u64* __restrict__ negPack) {
  __shared__ _Float16 Aj[256 * 128];  // j rows, XOR-swizzled
  __shared__ _Float16 Bi[256 * 128];  // i rows, XOR-swizzled
  __shared__ float2 nlj[256];

  const int t = threadIdx.x;
  const int jbase = (blockIdx.x >> 5) * 256;
  const int ibase = (blockIdx.x & 31) * 256;
  const int w = t >> 6, l = t & 63;

  // ---- stage 128KB (reg-staged, swizzled ds_write) ----
  {
    const int rsub = l >> 4;          // row within 4-row chunk
    const int b16 = (l & 15) << 4;    // byte col 0..240
    #pragma unroll
    for (int c = 0; c < 16; ++c) {
      int chunk = w * 16 + c;  // 0..127
      int row = (chunk & 63) * 4 + rsub;
      int gbase = (chunk < 64) ? jbase : ibase;
      _Float16* tile = (chunk < 64) ? Aj : Bi;
      half8 d = *(const half8*)((const char*)Eh + (size_t)(gbase + row) * 256 + b16);
      *(half8*)((char*)tile + row * 256 + (b16 ^ ((row & 7) << 4))) = d;
    }
    if (t < 256) nlj[t] = nl[jbase + t];
  }
  __syncthreads();

  const int jg = w >> 2, ig = w & 3;
  const int lane31 = l & 31, h = l >> 5;
  const int arow = jg * 128;  // wave j-tile base (4 tiles)
  const int brow = ig * 64;   // wave i-tile base (2 tiles)

  f32x16 acc[4][2];
  #pragma unroll
  for (int a = 0; a < 4; ++a)
    #pragma unroll
    for (int b = 0; b < 2; ++b)
      #pragma unroll
      for (int e = 0; e < 16; ++e) acc[a][b][e] = 0.0f;

  #pragma unroll
  for (int s = 0; s < 8; ++s) {
    const int bcol = s * 32 + h * 16;
    half8 af[4], bf[2];
    #pragma unroll
    for (int jt = 0; jt < 4; ++jt) {
      int row = arow + jt * 32 + lane31;
      af[jt] = *(const half8*)((const char*)Aj + row * 256 + (bcol ^ ((row & 7) << 4)));
    }
    #pragma unroll
    for (int it = 0; it < 2; ++it) {
      int row = brow + it * 32 + lane31;
      bf[it] = *(const half8*)((const char*)Bi + row * 256 + (bcol ^ ((row & 7) << 4)));
    }
    #pragma unroll
    for (int jt = 0; jt < 4; ++jt)
      #pragma unroll
      for (int it = 0; it < 2; ++it)
        acc[jt][it] = __builtin_amdgcn_mfma_f32_32x32x16_f16(af[jt], bf[it], acc[jt][it], 0, 0, 0);
  }

  // ---- epilogue: per-lane masked arg-reduce over 64 j's per i ----
  const int gi0 = ibase + brow + lane31;
  const int gi1 = gi0 + 32;
  const int li0 = lab[gi0];
  const int li1 = lab[gi1];
  float bpv0 = -3.0e38f, bnv0 = 3.0e38f, bpv1 = -3.0e38f, bnv1 = 3.0e38f;
  int bpj0 = 0, bnj0 = 0, bpj1 = 0, bnj1 = 0;

  #pragma unroll
  for (int jt = 0; jt < 4; ++jt) {
    #pragma unroll
    for (int r = 0; r < 16; ++r) {
      const int jrow = (r & 3) + 8 * (r >> 2) + 4 * h;  // C-row of reg r
      const int jloc = arow + jt * 32 + jrow;
      const int gj = jbase + jloc;
      float2 q = nlj[jloc];
      const float nj = q.x;
      const int lj = __float_as_int(q.y);
      // dist'' = ||xj||^2 - 2*g  (row-constant ||xi||^2 dropped: order-invariant)
      float d0 = fmaf(acc[jt][0][r], -2.0f, nj);
      float d1 = fmaf(acc[jt][1][r], -2.0f, nj);
      bool s0 = (lj == li0), s1 = (lj == li1);
      float pv0 = s0 ? d0 : -3.0e38f;
      float nv0 = s0 ? 3.0e38f : d0;
      float pv1 = s1 ? d1 : -3.0e38f;
      float nv1 = s1 ? 3.0e38f : d1;
      if (pv0 > bpv0) { bpv0 = pv0; bpj0 = gj; }
      if (nv0 < bnv0) { bnv0 = nv0; bnj0 = gj; }
      if (pv1 > bpv1) { bpv1 = pv1; bpj1 = gj; }
      if (nv1 < bnv1) { bnv1 = nv1; bnj1 = gj; }
    }
  }
  atomicMax(posPack + gi0, ((u64)fkey(bpv0) << 32) | (u64)(0xFFFFFFFFu - (unsigned)bpj0));
  atomicMin(negPack + gi0, ((u64)fkey(bnv0) << 32) | (u64)(unsigned)bnj0);
  atomicMax(posPack + gi1, ((u64)fkey(bpv1) << 32) | (u64)(0xFFFFFFFFu - (unsigned)bpj1));
  atomicMin(negPack + gi1, ((u64)fkey(bnv1) << 32) | (u64)(unsigned)bnj1);
}

// One wave per row: exact fp32 triplet term from the selected indices.
__global__ __launch_bounds__(256) void k_final(const float* __restrict__ E,
                                               const u64* __restrict__ posPack,
                                               const u64* __restrict__ negPack,
                                               float* __restrict__ rowLoss) {
  int i = (blockIdx.x * 256 + threadIdx.x) >> 6;
  int l = threadIdx.x & 63;
  int jp = (int)(0xFFFFFFFFu - (unsigned)(posPack[i] & 0xFFFFFFFFull));
  int jn = (int)(unsigned)(negPack[i] & 0xFFFFFFFFull);
  float2 a = *(const float2*)(E + i * Dd + l * 2);
  float2 p = *(const float2*)(E + jp * Dd + l * 2);
  float2 n = *(const float2*)(E + jn * Dd + l * 2);
  float dx = a.x - p.x + EPSf, dy = a.y - p.y + EPSf;
  float sap = dx * dx + dy * dy;
  dx = a.x - n.x + EPSf;
  dy = a.y - n.y + EPSf;
  float san = dx * dx + dy * dy;
  #pragma unroll
  for (int off = 32; off; off >>= 1) {
    sap += __shfl_xor(sap, off);
    san += __shfl_xor(san, off);
  }
  if (l == 0) rowLoss[i] = fmaxf(sqrtf(sap) - sqrtf(san) + MARGINf, 0.0f);
}

// Deterministic tree reduction -> mean.
__global__ __launch_bounds__(256) void k_reduce(const float* __restrict__ rowLoss,
                                                float* __restrict__ out) {
  __shared__ float s[256];
  int t = threadIdx.x;
  float sum = 0.f;
  for (int q = 0; q < 32; ++q) sum += rowLoss[t + 256 * q];
  s[t] = sum;
  __syncthreads();
  for (int off = 128; off; off >>= 1) {
    if (t < off) s[t] += s[t + off];
    __syncthreads();
  }
  if (t == 0) out[0] = s[0] * (1.0f / 8192.0f);
}

extern "C" void kernel_launch(void* const* d_in, const int* in_sizes, int n_in,
                              void* d_out, int out_size, void* d_ws, size_t ws_size,
                              hipStream_t stream) {
  const float* E = (const float*)d_in[0];
  const int* lab = (const int*)d_in[1];
  float* out = (float*)d_out;

  char* wsp = (char*)d_ws;
  u64* posPack = (u64*)wsp;                      // 64 KB
  u64* negPack = (u64*)(wsp + (64 << 10));       // 64 KB
  float2* nl = (float2*)(wsp + (128 << 10));     // 64 KB
  float* rowLoss = (float*)(wsp + (192 << 10));  // 32 KB
  _Float16* Eh = (_Float16*)(wsp + (256 << 10)); // 2 MB

  k_prep<<<2048, 256, 0, stream>>>(E, lab, Eh, nl, posPack, negPack);
  k_gemm<<<1024, 512, 0, stream>>>(Eh, nl, lab, posPack, negPack);
  k_final<<<2048, 256, 0, stream>>>(E, posPack, negPack, rowLoss);
  k_reduce<<<1, 256, 0, stream>>>(rowLoss, out);
}

// Round 3
// 49.140 us; speedup vs baseline: 7.3917x; 1.1479x over previous
//
#include <hip/hip_runtime.h>
#include <cstdint>

typedef unsigned long long u64;
typedef _Float16 half8 __attribute__((ext_vector_type(8)));
typedef float f32x4 __attribute__((ext_vector_type(4)));

static constexpr int Dd = 128;
static constexpr float EPSf = 1e-6f;
static constexpr float MARGINf = 1.0f;
static constexpr float BIGf = 3.0e38f;

// Monotonic map fp32 -> u32 (total order matching float compare).
__device__ __forceinline__ unsigned fkey(float f) {
  unsigned b = __float_as_uint(f);
  return (b & 0x80000000u) ? ~b : (b | 0x80000000u);
}

// One wave per row: fp32 norm (exact), fp16 convert, norm+label pack, init packs.
__global__ __launch_bounds__(256) void k_prep(const float* __restrict__ E,
                                              const int* __restrict__ lab,
                                              _Float16* __restrict__ Eh,
                                              float2* __restrict__ nl,
                                              u64* __restrict__ posPack,
                                              u64* __restrict__ negPack) {
  int row = (blockIdx.x * 256 + threadIdx.x) >> 6;
  int l = threadIdx.x & 63;
  float2 v = *(const float2*)(E + row * Dd + l * 2);
  union { _Float16 h[2]; unsigned u; } cv;
  cv.h[0] = (_Float16)v.x;
  cv.h[1] = (_Float16)v.y;
  *(unsigned*)(Eh + row * Dd + l * 2) = cv.u;
  float s = v.x * v.x + v.y * v.y;
  #pragma unroll
  for (int off = 32; off; off >>= 1) s += __shfl_xor(s, off);
  if (l == 0) {
    float2 q;
    q.x = s;
    q.y = __int_as_float(lab[row]);
    nl[row] = q;
    posPack[row] = 0ull;
    negPack[row] = ~0ull;
  }
}

// 256x256 pair tile: Gram via 16x16x32 f16 MFMA (rows=j, cols=i) + fused
// per-lane masked arg-reductions with mantissa-stuffed indices.
__global__ __launch_bounds__(512, 2) void k_gemm(const _Float16* __restrict__ Eh,
                                                 const float2* __restrict__ nl,
                                                 const int* __restrict__ lab,
                                                 u64* __restrict__ posPack,
                                                 u64* __restrict__ negPack) {
  __shared__ __align__(1024) _Float16 As[256 * 128];  // j rows, XOR-swizzled
  __shared__ __align__(1024) _Float16 Bs[256 * 128];  // i rows, XOR-swizzled
  __shared__ __align__(16) float2 nlj[256];

  const int t = threadIdx.x;
  const int w = t >> 6, l = t & 63;
  const int jbase = (blockIdx.x >> 5) * 256;
  const int ibase = (blockIdx.x & 31) * 256;
  const int lane15 = l & 15, lg = l >> 4;
  const int iw = w & 3, jw = w >> 2;  // 4 i-waves x 2 j-waves

  // ---- stage 128KB: coalesced global reads, swizzled ds_write ----
  {
    const int cp = lane15 << 4;  // byte col 0..240
    #pragma unroll
    for (int ci = 0; ci < 16; ++ci) {
      int chunk = w * 16 + ci;          // 0..127
      int r = (chunk & 63) * 4 + lg;    // row 0..255
      int gbase = (chunk < 64) ? jbase : ibase;
      _Float16* tile = (chunk < 64) ? As : Bs;
      half8 v = *(const half8*)((const char*)Eh + (size_t)(gbase + r) * 256 + cp);
      *(half8*)((char*)tile + r * 256 + (cp ^ ((r & 7) << 4))) = v;
    }
    if (t < 256) nlj[t] = nl[jbase + t];
  }

  // i-side labels (overlap with staging drain)
  int li[4];
  #pragma unroll
  for (int it = 0; it < 4; ++it) li[it] = lab[ibase + iw * 64 + it * 16 + lane15];

  __syncthreads();

  // ---- compute: wave-tile 128j x 64i = 8x4 16x16 tiles ----
  f32x4 acc[8][4];
  #pragma unroll
  for (int a = 0; a < 8; ++a)
    #pragma unroll
    for (int b = 0; b < 4; ++b) acc[a][b] = (f32x4){0.f, 0.f, 0.f, 0.f};

  #pragma unroll
  for (int ks = 0; ks < 4; ++ks) {
    const int bc = ks * 64 + lg * 16;  // byte col of this lane's K-slice
    half8 af[8], bf[4];
    #pragma unroll
    for (int jt = 0; jt < 8; ++jt) {
      int r = jw * 128 + jt * 16 + lane15;
      af[jt] = *(const half8*)((const char*)As + r * 256 + (bc ^ ((r & 7) << 4)));
    }
    #pragma unroll
    for (int it = 0; it < 4; ++it) {
      int r = iw * 64 + it * 16 + lane15;
      bf[it] = *(const half8*)((const char*)Bs + r * 256 + (bc ^ ((r & 7) << 4)));
    }
    #pragma unroll
    for (int jt = 0; jt < 8; ++jt)
      #pragma unroll
      for (int it = 0; it < 4; ++it)
        acc[jt][it] = __builtin_amdgcn_mfma_f32_16x16x32_f16(af[jt], bf[it], acc[jt][it], 0, 0, 0);
  }

  // ---- epilogue: dist'' = nj - 2g (ni dropped: row-constant), index stuffed
  // into low 8 mantissa bits, pure fmax/fmin (-> max3/min3) reductions ----
  float bp[4], bn[4];
  #pragma unroll
  for (int it = 0; it < 4; ++it) { bp[it] = -BIGf; bn[it] = BIGf; }

  #pragma unroll
  for (int jt = 0; jt < 8; ++jt) {
    const int jr0 = jw * 128 + jt * 16 + lg * 4;  // 4 consecutive local j
    float4 q01 = *(const float4*)(nlj + jr0);      // {n0,l0,n1,l1}
    float4 q23 = *(const float4*)(nlj + jr0 + 2);
    float nj[4] = {q01.x, q01.z, q23.x, q23.z};
    int ljv[4] = {__float_as_int(q01.y), __float_as_int(q01.w),
                  __float_as_int(q23.y), __float_as_int(q23.w)};
    #pragma unroll
    for (int it = 0; it < 4; ++it) {
      float pc[4], nc[4];
      #pragma unroll
      for (int r = 0; r < 4; ++r) {
        float d = fmaf(acc[jt][it][r], -2.0f, nj[r]);
        float dv = __uint_as_float((__float_as_uint(d) & 0xFFFFFF00u) |
                                   (unsigned)(jr0 + r));
        bool sim = (ljv[r] == li[it]);
        pc[r] = sim ? dv : -BIGf;
        nc[r] = sim ? BIGf : dv;
      }
      bp[it] = fmaxf(bp[it], fmaxf(fmaxf(pc[0], pc[1]), fmaxf(pc[2], pc[3])));
      bn[it] = fminf(bn[it], fminf(fminf(nc[0], nc[1]), fminf(nc[2], nc[3])));
    }
  }

  // ---- merge the 4 row-group lanes (same i, different j's), then atomics ----
  #pragma unroll
  for (int it = 0; it < 4; ++it) {
    #pragma unroll
    for (int s = 16; s < 64; s <<= 1) {
      bp[it] = fmaxf(bp[it], __shfl_xor(bp[it], s));
      bn[it] = fminf(bn[it], __shfl_xor(bn[it], s));
    }
  }
  if (l < 16) {
    #pragma unroll
    for (int it = 0; it < 4; ++it) {
      int gi = ibase + iw * 64 + it * 16 + lane15;
      int jp = jbase + (int)(__float_as_uint(bp[it]) & 255u);
      int jn = jbase + (int)(__float_as_uint(bn[it]) & 255u);
      atomicMax(posPack + gi, ((u64)fkey(bp[it]) << 32) | (u64)(0xFFFFFFFFu - (unsigned)jp));
      atomicMin(negPack + gi, ((u64)fkey(bn[it]) << 32) | (u64)(unsigned)jn);
    }
  }
}

// One wave per row: exact fp32 triplet term from the selected indices.
__global__ __launch_bounds__(256) void k_final(const float* __restrict__ E,
                                               const u64* __restrict__ posPack,
                                               const u64* __restrict__ negPack,
                                               float* __restrict__ rowLoss) {
  int i = (blockIdx.x * 256 + threadIdx.x) >> 6;
  int l = threadIdx.x & 63;
  int jp = (int)(0xFFFFFFFFu - (unsigned)(posPack[i] & 0xFFFFFFFFull));
  int jn = (int)(unsigned)(negPack[i] & 0xFFFFFFFFull);
  float2 a = *(const float2*)(E + i * Dd + l * 2);
  float2 p = *(const float2*)(E + jp * Dd + l * 2);
  float2 n = *(const float2*)(E + jn * Dd + l * 2);
  float dx = a.x - p.x + EPSf, dy = a.y - p.y + EPSf;
  float sap = dx * dx + dy * dy;
  dx = a.x - n.x + EPSf;
  dy = a.y - n.y + EPSf;
  float san = dx * dx + dy * dy;
  #pragma unroll
  for (int off = 32; off; off >>= 1) {
    sap += __shfl_xor(sap, off);
    san += __shfl_xor(san, off);
  }
  if (l == 0) rowLoss[i] = fmaxf(sqrtf(sap) - sqrtf(san) + MARGINf, 0.0f);
}

// Deterministic tree reduction -> mean.
__global__ __launch_bounds__(256) void k_reduce(const float* __restrict__ rowLoss,
                                                float* __restrict__ out) {
  __shared__ float s[256];
  int t = threadIdx.x;
  float sum = 0.f;
  for (int q = 0; q < 32; ++q) sum += rowLoss[t + 256 * q];
  s[t] = sum;
  __syncthreads();
  for (int off = 128; off; off >>= 1) {
    if (t < off) s[t] += s[t + off];
    __syncthreads();
  }
  if (t == 0) out[0] = s[0] * (1.0f / 8192.0f);
}

extern "C" void kernel_launch(void* const* d_in, const int* in_sizes, int n_in,
                              void* d_out, int out_size, void* d_ws, size_t ws_size,
                              hipStream_t stream) {
  const float* E = (const float*)d_in[0];
  const int* lab = (const int*)d_in[1];
  float* out = (float*)d_out;

  char* wsp = (char*)d_ws;
  u64* posPack = (u64*)wsp;                      // 64 KB
  u64* negPack = (u64*)(wsp + (64 << 10));       // 64 KB
  float2* nl = (float2*)(wsp + (128 << 10));     // 64 KB
  float* rowLoss = (float*)(wsp + (192 << 10));  // 32 KB
  _Float16* Eh = (_Float16*)(wsp + (256 << 10)); // 2 MB

  k_prep<<<2048, 256, 0, stream>>>(E, lab, Eh, nl, posPack, negPack);
  k_gemm<<<1024, 512, 0, stream>>>(Eh, nl, lab, posPack, negPack);
  k_final<<<2048, 256, 0, stream>>>(E, posPack, negPack, rowLoss);
  k_reduce<<<1, 256, 0, stream>>>(rowLoss, out);
}

// Round 4
// 48.061 us; speedup vs baseline: 7.5577x; 1.0224x over previous
//
#include <hip/hip_runtime.h>
#include <cstdint>

typedef unsigned long long u64;
typedef _Float16 half8 __attribute__((ext_vector_type(8)));
typedef float f32x4 __attribute__((ext_vector_type(4)));

static constexpr int Dd = 128;
static constexpr float EPSf = 1e-6f;
static constexpr float MARGINf = 1.0f;
static constexpr float BIGf = 3.0e38f;

// Monotonic map fp32 -> u32 (total order matching float compare).
__device__ __forceinline__ unsigned fkey(float f) {
  unsigned b = __float_as_uint(f);
  return (b & 0x80000000u) ? ~b : (b | 0x80000000u);
}

// Async global->LDS, 16B per lane. LDS dest is wave-uniform base + lane*16;
// global source is per-lane (pre-swizzled for the XOR LDS layout).
__device__ __forceinline__ void gl_lds16(const void* g, void* l) {
  __builtin_amdgcn_global_load_lds(
      (const __attribute__((address_space(1))) unsigned int*)g,
      (__attribute__((address_space(3))) unsigned int*)l, 16, 0, 0);
}

// One wave per row: fp32 norm (exact), fp16 convert, norm+label pack.
__global__ __launch_bounds__(256) void k_prep(const float* __restrict__ E,
                                              const int* __restrict__ lab,
                                              _Float16* __restrict__ Eh,
                                              float2* __restrict__ nl) {
  int row = (blockIdx.x * 256 + threadIdx.x) >> 6;
  int l = threadIdx.x & 63;
  float2 v = *(const float2*)(E + row * Dd + l * 2);
  union { _Float16 h[2]; unsigned u; } cv;
  cv.h[0] = (_Float16)v.x;
  cv.h[1] = (_Float16)v.y;
  *(unsigned*)(Eh + row * Dd + l * 2) = cv.u;
  float s = v.x * v.x + v.y * v.y;
  #pragma unroll
  for (int off = 32; off; off >>= 1) s += __shfl_xor(s, off);
  if (l == 0) {
    float2 q;
    q.x = s;
    q.y = __int_as_float(lab[row]);
    nl[row] = q;
  }
}

// Block = 128 i-rows (register-resident) x 1024 j-rows streamed as 4 LDS
// double-buffered tiles of 256. Per-lane running masked arg-reductions,
// no atomics; per-strip partials merged in k_final.
__global__ __launch_bounds__(512, 2) void k_gemm(const _Float16* __restrict__ Eh,
                                                 const float2* __restrict__ nl,
                                                 const int* __restrict__ lab,
                                                 u64* __restrict__ posPart,
                                                 u64* __restrict__ negPart) {
  __shared__ __align__(16) _Float16 jA[2][256 * 128];  // 2 x 64KB, XOR-swizzled rows
  __shared__ __align__(16) float2 jNL[2][256];         // 2 x 2KB
  __shared__ float sc[2][4][128];                      // pos/neg x jw x i-local

  const int t = threadIdx.x;
  const int w = t >> 6, l = t & 63;
  const int lane15 = l & 15, lg = l >> 4;
  const int ig = w & 1, jw = w >> 1;  // 2 i-groups x 4 j-groups
  const int ip = blockIdx.x & 63, js = blockIdx.x >> 6;
  const int ibase = ip * 128;
  const int jbase = js * 1024;

  // ---- prologue: issue i-panel -> jA[0], tile0 -> jA[1], nl0 -> jNL[1] ----
  #pragma unroll
  for (int qi = 0; qi < 4; ++qi) {
    int q = w * 4 + qi;          // 0..31 (32KB i-panel)
    int row = q * 4 + lg;        // 0..127
    gl_lds16((const char*)Eh + (size_t)(ibase + row) * 256 + ((lane15 << 4) ^ ((row & 7) << 4)),
             (char*)&jA[0][0] + q * 1024);
  }
  #pragma unroll
  for (int qi = 0; qi < 8; ++qi) {
    int q = w * 8 + qi;          // 0..63 (64KB j-tile)
    int row = q * 4 + lg;        // 0..255
    gl_lds16((const char*)Eh + (size_t)(jbase + row) * 256 + ((lane15 << 4) ^ ((row & 7) << 4)),
             (char*)&jA[1][0] + q * 1024);
  }
  if (w < 2)
    gl_lds16((const char*)nl + (size_t)jbase * 8 + w * 1024 + l * 16,
             (char*)&jNL[1][0] + w * 1024);

  // i-side labels (direct global, overlaps staging)
  int li[4];
  #pragma unroll
  for (int it = 0; it < 4; ++it) li[it] = lab[ibase + ig * 64 + it * 16 + lane15];

  __syncthreads();  // compiler drains vmcnt(0): i-panel + tile0 landed

  // ---- load i-fragments to registers (once) ----
  half8 bf[4][4];
  #pragma unroll
  for (int it = 0; it < 4; ++it) {
    #pragma unroll
    for (int ks = 0; ks < 4; ++ks) {
      int r = ig * 64 + it * 16 + lane15;
      int bc = ks * 64 + lg * 16;
      bf[it][ks] = *(const half8*)((const char*)&jA[0][0] + r * 256 + (bc ^ ((r & 7) << 4)));
    }
  }
  __syncthreads();  // all waves done with jA[0]; it becomes j-buffer

  float bp[4], bn[4];
  #pragma unroll
  for (int it = 0; it < 4; ++it) { bp[it] = -BIGf; bn[it] = BIGf; }

  // ---- j-loop: 4 tiles of 256, double-buffered ----
  #pragma unroll
  for (int tt = 0; tt < 4; ++tt) {
    const int cur = 1 - (tt & 1);
    const int nxt = tt & 1;

    if (tt < 3) {  // prefetch tile tt+1 into the other buffer
      const int jr = jbase + (tt + 1) * 256;
      #pragma unroll
      for (int qi = 0; qi < 8; ++qi) {
        int q = w * 8 + qi;
        int row = q * 4 + lg;
        gl_lds16((const char*)Eh + (size_t)(jr + row) * 256 + ((lane15 << 4) ^ ((row & 7) << 4)),
                 (char*)&jA[nxt][0] + q * 1024);
      }
      if (w < 2)
        gl_lds16((const char*)nl + (size_t)jr * 8 + w * 1024 + l * 16,
                 (char*)&jNL[nxt][0] + w * 1024);
    }

    // compute 128i x 256j on buf cur; wave-tile 64i x 64j
    f32x4 acc[4][4];
    #pragma unroll
    for (int a = 0; a < 4; ++a)
      #pragma unroll
      for (int b = 0; b < 4; ++b) acc[a][b] = (f32x4){0.f, 0.f, 0.f, 0.f};

    #pragma unroll
    for (int ks = 0; ks < 4; ++ks) {
      const int bc = ks * 64 + lg * 16;
      half8 af[4];
      #pragma unroll
      for (int jt = 0; jt < 4; ++jt) {
        int r = jw * 64 + jt * 16 + lane15;
        af[jt] = *(const half8*)((const char*)&jA[cur][0] + r * 256 + (bc ^ ((r & 7) << 4)));
      }
      #pragma unroll
      for (int jt = 0; jt < 4; ++jt)
        #pragma unroll
        for (int it = 0; it < 4; ++it)
          acc[jt][it] = __builtin_amdgcn_mfma_f32_16x16x32_f16(af[jt], bf[it][ks], acc[jt][it], 0, 0, 0);
    }

    // epilogue: d'' = nj - 2g (ni dropped: row-constant), 10-bit strip-local
    // index stuffed in the mantissa, running fmax/fmin
    const unsigned tb = (unsigned)(tt * 256 + jw * 64 + lg * 4);
    #pragma unroll
    for (int jt = 0; jt < 4; ++jt) {
      const int jr0 = jw * 64 + jt * 16 + lg * 4;
      float4 q01 = *(const float4*)&jNL[cur][jr0];
      float4 q23 = *(const float4*)&jNL[cur][jr0 + 2];
      const float njv[4] = {q01.x, q01.z, q23.x, q23.z};
      const int ljv[4] = {__float_as_int(q01.y), __float_as_int(q01.w),
                          __float_as_int(q23.y), __float_as_int(q23.w)};
      const unsigned ib = tb + (unsigned)(jt * 16);
      #pragma unroll
      for (int it = 0; it < 4; ++it) {
        float pcv[4], ncv[4];
        #pragma unroll
        for (int r = 0; r < 4; ++r) {
          float d = fmaf(acc[jt][it][r], -2.0f, njv[r]);
          float dv = __uint_as_float((__float_as_uint(d) & 0xFFFFFC00u) | (ib + (unsigned)r));
          bool sim = (ljv[r] == li[it]);
          pcv[r] = sim ? dv : -BIGf;
          ncv[r] = sim ? BIGf : dv;
        }
        bp[it] = fmaxf(bp[it], fmaxf(fmaxf(pcv[0], pcv[1]), fmaxf(pcv[2], pcv[3])));
        bn[it] = fminf(bn[it], fminf(fminf(ncv[0], ncv[1]), fminf(ncv[2], ncv[3])));
      }
    }
    __syncthreads();  // drains prefetch (vmcnt) + all reads of cur done
  }

  // ---- merge lg lanes (same i, different j) ----
  #pragma unroll
  for (int it = 0; it < 4; ++it) {
    #pragma unroll
    for (int s = 16; s < 64; s <<= 1) {
      bp[it] = fmaxf(bp[it], __shfl_xor(bp[it], s));
      bn[it] = fminf(bn[it], __shfl_xor(bn[it], s));
    }
  }
  if (l < 16) {
    #pragma unroll
    for (int it = 0; it < 4; ++it) {
      sc[0][jw][ig * 64 + it * 16 + lane15] = bp[it];
      sc[1][jw][ig * 64 + it * 16 + lane15] = bn[it];
    }
  }
  __syncthreads();

  // ---- cross-wave merge + per-strip partial write (no atomics) ----
  if (t < 128) {
    float p = fmaxf(fmaxf(sc[0][0][t], sc[0][1][t]), fmaxf(sc[0][2][t], sc[0][3][t]));
    float n = fminf(fminf(sc[1][0][t], sc[1][1][t]), fminf(sc[1][2][t], sc[1][3][t]));
    unsigned jp = (unsigned)jbase + (__float_as_uint(p) & 1023u);
    unsigned jn = (unsigned)jbase + (__float_as_uint(n) & 1023u);
    posPart[(size_t)js * 8192 + ibase + t] =
        ((u64)fkey(p) << 32) | (u64)(0xFFFFFFFFu - jp);
    negPart[(size_t)js * 8192 + ibase + t] = ((u64)fkey(n) << 32) | (u64)jn;
  }
}

// One wave per row: merge 8 strip-partials, exact fp32 triplet term.
__global__ __launch_bounds__(256) void k_final(const float* __restrict__ E,
                                               const u64* __restrict__ posPart,
                                               const u64* __restrict__ negPart,
                                               float* __restrict__ rowLoss) {
  int i = (blockIdx.x * 256 + threadIdx.x) >> 6;
  int l = threadIdx.x & 63;
  u64 pp = 0ull, np = ~0ull;
  #pragma unroll
  for (int s = 0; s < 8; ++s) {
    u64 a = posPart[(size_t)s * 8192 + i];
    u64 b = negPart[(size_t)s * 8192 + i];
    pp = pp > a ? pp : a;
    np = np < b ? np : b;
  }
  int jp = (int)(0xFFFFFFFFu - (unsigned)(pp & 0xFFFFFFFFull));
  int jn = (int)(unsigned)(np & 0xFFFFFFFFull);
  float2 a = *(const float2*)(E + i * Dd + l * 2);
  float2 p = *(const float2*)(E + jp * Dd + l * 2);
  float2 n = *(const float2*)(E + jn * Dd + l * 2);
  float dx = a.x - p.x + EPSf, dy = a.y - p.y + EPSf;
  float sap = dx * dx + dy * dy;
  dx = a.x - n.x + EPSf;
  dy = a.y - n.y + EPSf;
  float san = dx * dx + dy * dy;
  #pragma unroll
  for (int off = 32; off; off >>= 1) {
    sap += __shfl_xor(sap, off);
    san += __shfl_xor(san, off);
  }
  if (l == 0) rowLoss[i] = fmaxf(sqrtf(sap) - sqrtf(san) + MARGINf, 0.0f);
}

// Deterministic tree reduction -> mean.
__global__ __launch_bounds__(256) void k_reduce(const float* __restrict__ rowLoss,
                                                float* __restrict__ out) {
  __shared__ float s[256];
  int t = threadIdx.x;
  float sum = 0.f;
  for (int q = 0; q < 32; ++q) sum += rowLoss[t + 256 * q];
  s[t] = sum;
  __syncthreads();
  for (int off = 128; off; off >>= 1) {
    if (t < off) s[t] += s[t + off];
    __syncthreads();
  }
  if (t == 0) out[0] = s[0] * (1.0f / 8192.0f);
}

extern "C" void kernel_launch(void* const* d_in, const int* in_sizes, int n_in,
                              void* d_out, int out_size, void* d_ws, size_t ws_size,
                              hipStream_t stream) {
  const float* E = (const float*)d_in[0];
  const int* lab = (const int*)d_in[1];
  float* out = (float*)d_out;

  char* wsp = (char*)d_ws;
  u64* posPart = (u64*)wsp;                        // 8*8192*8 = 512KB
  u64* negPart = (u64*)(wsp + (512 << 10));        // 512KB
  float2* nl = (float2*)(wsp + (1024 << 10));      // 64KB
  float* rowLoss = (float*)(wsp + (1088 << 10));   // 32KB
  _Float16* Eh = (_Float16*)(wsp + (1152 << 10));  // 2MB

  k_prep<<<2048, 256, 0, stream>>>(E, lab, Eh, nl);
  k_gemm<<<512, 512, 0, stream>>>(Eh, nl, lab, posPart, negPart);
  k_final<<<2048, 256, 0, stream>>>(E, posPart, negPart, rowLoss);
  k_reduce<<<1, 256, 0, stream>>>(rowLoss, out);
}